// Round 10
// baseline (10756.354 us; speedup 1.0000x reference)
//
#include <hip/hip_runtime.h>
#include <math.h>
#include <limits.h>

typedef __attribute__((ext_vector_type(8))) short short8v;
typedef __attribute__((ext_vector_type(4))) float float4v;

#define BB 64
#define TT 1024
#define DD 128
#define HH 512

// ---- ushort (bf16) region: weights (element offsets) ----
#define O_WHH_HI  0u         // [4 units][1536][512]
#define O_WHH_LO  3145728u
#define O_WIH1_HI 6291456u   // [2 dir][1536][512]
#define O_WIH1_LO 7864320u
#define O_WIH0_HI 9437184u   // [2 dir][1536][128]
#define O_WIH0_LO 9830400u   // ends at 10223616 ushorts
// ---- 4-byte-word region (ws as unsigned*/float*), word offsets ----
// h planes dense [k][64 b]: word = k*64 + b  (R6 proven layout)
#define O_H0_W    5111808u   // [2 dir][4 slot] planes of 32768 words
#define O_H1_W    5373952u   // [2 dir][2 slot]
#define O_FLAGS_W 5505024u   // 512 ints: leaf[u][g] at flags[u*128 + g*16] (monotonic)
#define O_FCIN_W  5505536u   // 131072 f
#define O_FC1O_W  5636608u   //  65536 f
#define O_FC2O_W  5702144u   //  32768 f
#define H_ZERO_W  393216u    // words to zero from O_H0_W

#define DYN_LDS   69632      // [8 waves][32 rows] x stride-68 f32 (measured conflict-free)

struct PP {
  const float* x;
  const float* bih[4];
  const float* bhh[4];
  unsigned short* wsu;   // weight planes
  unsigned* ws32;        // packed h region
  int* flags;
};

__device__ __forceinline__ unsigned short bf16_rne(float f) {
  unsigned u = __builtin_bit_cast(unsigned, f);
  u += 0x7FFFu + ((u >> 16) & 1u);
  return (unsigned short)(u >> 16);
}
__device__ __forceinline__ float bf16_f(unsigned short h) {
  unsigned u = ((unsigned)h) << 16;
  return __builtin_bit_cast(float, u);
}
__device__ __forceinline__ float4v MF(short8v a, short8v b, float4v c) {
  return __builtin_amdgcn_mfma_f32_16x16x32_bf16(a, b, c, 0, 0, 0);
}
// agent-scope relaxed (coherence point, no fences) — R6 proven path
__device__ __forceinline__ unsigned ald_w(const unsigned* p) {
  return __hip_atomic_load(p, __ATOMIC_RELAXED, __HIP_MEMORY_SCOPE_AGENT);
}
__device__ __forceinline__ void ast_w(unsigned* p, unsigned v) {
  __hip_atomic_store(p, v, __ATOMIC_RELAXED, __HIP_MEMORY_SCOPE_AGENT);
}
// load B fragment (8 k-elems for lane's batch col b) from dense [k][64] plane
__device__ __forceinline__ void ldB(const unsigned* base, int ko, int b,
                                    short8v& Bh, short8v& Bl) {
  #pragma unroll
  for (int e = 0; e < 8; ++e) {
    const unsigned w = ald_w(base + (unsigned)(ko + e) * 64u + (unsigned)b);
    Bh[e] = (short)(w >> 16);
    Bl[e] = (short)(w & 0xFFFFu);
  }
}

// row within stacked-[3*512] W for local row rl (0..31); -1 => zero frag
__device__ __forceinline__ int rowmap(int rl, int inp, int j0) {
  if (rl < 8)  return j0 + rl;
  if (rl < 16) return 512 + j0 + (rl - 8);
  if (rl < 24) return inp ? (1024 + j0 + rl - 16) : -1;
  return inp ? -1 : (1024 + j0 + rl - 24);
}
__device__ __forceinline__ short8v ldA(const unsigned short* W, int K, int row, int kofs) {
  return *(const short8v*)(W + (size_t)row * K + kofs);
}

// 256 blocks x 512 thr. u=bid>>6 (dir*2+layer), jt=bid&63 -> 8 j's.
// 8 waves split K; MFMA C[32 rows x 64 b]; rows: 0-7 r, 8-15 z, 16-23 n_ih, 24-31 n_hh.
// Sync: fine-grained dataflow. leaf[u][g] = monotonic count of group-g block
// step-completions (L0 count after step s = 8(s+1); L1 after step s = 8s).
// Each wave polls ONLY the group counter(s) covering its K-slice; wave0 also
// carries the (lag-2/3) anti-dependency checks. No unit-wide barrier.
__global__ __launch_bounds__(512) void gru_mfma(PP p) {
  extern __shared__ float red[];  // [8][32] stride 68
  const int bid = blockIdx.x;
  const int u = bid >> 6, dir = u >> 1, layer = u & 1;
  const int jt = bid & 63, j0 = jt * 8;
  const int tid = threadIdx.x, wid = tid >> 6, lane = tid & 63;
  const int lr = lane & 15, lq = lane >> 4;
  unsigned short* wsu = p.wsu;
  unsigned* ws32 = p.ws32;

  // ---- preload A fragments (weights) into VGPRs (normal cached loads) ----
  short8v Ah[2][4], Al[2][4];
  #pragma unroll
  for (int mt = 0; mt < 2; ++mt)
    #pragma unroll
    for (int i = 0; i < 4; ++i) { Ah[mt][i] = (short8v)0; Al[mt][i] = (short8v)0; }

  if (layer) {
    const int inp = (wid < 4);  // waves 0-3: input part (Wih_l1), 4-7: hidden (Whh)
    const unsigned short* Whi = inp ? (wsu + O_WIH1_HI + dir * 786432u)
                                    : (wsu + O_WHH_HI + (unsigned)u * 786432u);
    const unsigned short* Wlo = inp ? (wsu + O_WIH1_LO + dir * 786432u)
                                    : (wsu + O_WHH_LO + (unsigned)u * 786432u);
    #pragma unroll
    for (int i = 0; i < 4; ++i) {
      const int kst_m = (wid * 4 + i) - (inp ? 0 : 16);
      const int kofs = kst_m * 32 + lq * 8;
      #pragma unroll
      for (int mt = 0; mt < 2; ++mt) {
        const int row = rowmap(mt * 16 + lr, inp, j0);
        if (row >= 0) { Ah[mt][i] = ldA(Whi, 512, row, kofs); Al[mt][i] = ldA(Wlo, 512, row, kofs); }
      }
    }
  } else {
    const unsigned short* Whi = wsu + O_WHH_HI + (unsigned)u * 786432u;
    const unsigned short* Wlo = wsu + O_WHH_LO + (unsigned)u * 786432u;
    #pragma unroll
    for (int i = 0; i < 2; ++i) {
      const int kofs = (wid * 2 + i) * 32 + lq * 8;
      #pragma unroll
      for (int mt = 0; mt < 2; ++mt) {
        const int row = rowmap(mt * 16 + lr, 0, j0);
        if (row >= 0) { Ah[mt][i] = ldA(Whi, 512, row, kofs); Al[mt][i] = ldA(Wlo, 512, row, kofs); }
      }
    }
    if (wid < 4) {  // x part: K=128, wave wid owns kst wid
      const unsigned short* Xhi = wsu + O_WIH0_HI + dir * 196608u;
      const unsigned short* Xlo = wsu + O_WIH0_LO + dir * 196608u;
      const int kofs = wid * 32 + lq * 8;
      #pragma unroll
      for (int mt = 0; mt < 2; ++mt) {
        const int row = rowmap(mt * 16 + lr, 1, j0);
        if (row >= 0) { Ah[mt][2] = ldA(Xhi, 128, row, kofs); Al[mt][2] = ldA(Xlo, 128, row, kofs); }
      }
    }
  }

  // ---- gate-stage mapping (R6): jth = tid>>6 (j), bth = tid&63 (batch) ----
  const int jth = tid >> 6, bth = tid & 63;
  const float br   = p.bih[u][j0 + jth] + p.bhh[u][j0 + jth];
  const float bz   = p.bih[u][512 + j0 + jth] + p.bhh[u][512 + j0 + jth];
  const float bnih = p.bih[u][1024 + j0 + jth];
  const float bnhh = p.bhh[u][1024 + j0 + jth];

  const int usib = layer ? (u - 1) : (u + 1);
  int* Lown = p.flags + u * 128;     // 8 counters, 64B apart
  int* Lsib = p.flags + usib * 128;
  const int g8 = jt >> 3;            // this block's producer group
  const int sBeg = layer ? 1 : 0;
  const int sEnd = layer ? TT : (TT - 1);

  for (int s = sBeg; s <= sEnd; ++s) {
    const int t = layer ? (s - 1) : s;

    float4v acc[2][4];
    #pragma unroll
    for (int mt = 0; mt < 2; ++mt)
      #pragma unroll
      for (int nt = 0; nt < 4; ++nt) acc[mt][nt] = (float4v)0.f;

    // ---- x contribution BEFORE the polls (independent of h) ----
    if (!layer && wid < 4) {
      const int tx = dir ? (TT - 1 - t) : t;
      const int ko = wid * 32 + lq * 8;
      #pragma unroll
      for (int nt = 0; nt < 4; ++nt) {
        const int b = nt * 16 + lr;
        const float* xs = p.x + ((size_t)b * TT + tx) * DD + ko;
        short8v Bh, Bl;
        #pragma unroll
        for (int e = 0; e < 8; ++e) {
          const float xv = xs[e];
          const unsigned short hh = bf16_rne(xv);
          Bh[e] = (short)hh;
          Bl[e] = (short)bf16_rne(xv - bf16_f(hh));
        }
        #pragma unroll
        for (int mt = 0; mt < 2; ++mt) {
          acc[mt][nt] = MF(Ah[mt][2], Bh, acc[mt][nt]);
          acc[mt][nt] = MF(Al[mt][2], Bh, acc[mt][nt]);
          acc[mt][nt] = MF(Ah[mt][2], Bl, acc[mt][nt]);
        }
      }
    }

    // ---- per-wave fine-grained dependency poll (relaxed, no fences) ----
    // L0 wave w needs own group w @ step s-1 (count >= 8s).
    // L1 wave w<4 needs sib groups {2w,2w+1} @ s-1 (>= 8s);
    //    wave w>=4 needs own groups {2(w-4),2(w-4)+1} @ s-1 (>= 8(s-1)).
    // wave0 extra (anti-deps, lag>=1): L0: own all >= 8(s-2), sib all >= 8(s-3);
    //                                  L1: own all >= 8(s-1).
    {
      const int* paddr = Lown;
      int thr = INT_MIN;
      if (!layer) {
        if (wid == 0) {
          if (lane < 8)       { paddr = Lown + lane * 16;       thr = (lane == 0) ? 8 * s : 8 * (s - 2); }
          else if (lane < 16) { paddr = Lsib + (lane - 8) * 16; thr = 8 * (s - 3); }
        } else {
          paddr = Lown + wid * 16; thr = 8 * s;
        }
      } else {
        if (wid == 0) {
          if (lane < 8)       { paddr = Lown + lane * 16;       thr = 8 * (s - 1); }
          else if (lane < 10) { paddr = Lsib + (lane - 8) * 16; thr = 8 * s; }
        } else if (wid < 4) {
          if (lane < 2) { paddr = Lsib + (2 * wid + lane) * 16; thr = 8 * s; }
        } else {
          if (lane < 2) { paddr = Lown + (2 * (wid - 4) + lane) * 16; thr = 8 * (s - 1); }
        }
      }
      int iter = 0;
      while (true) {
        const int v = __hip_atomic_load(paddr, __ATOMIC_RELAXED, __HIP_MEMORY_SCOPE_AGENT);
        if (__all(v >= thr)) break;
        if (++iter > 300000) break;   // failsafe: no hang (results wrong if hit)
        __builtin_amdgcn_s_sleep(1);
      }
    }

    // ---- h contributions (dense [k][64] planes, sc1 loads) ----
    const unsigned* h0p = ws32 + O_H0_W + ((unsigned)dir * 4 + ((s - 1) & 3)) * 32768u;
    if (layer) {
      const int inp = (wid < 4);
      const unsigned* bbase = inp ? h0p
          : (ws32 + O_H1_W + ((unsigned)dir * 2 + (s & 1)) * 32768u);
      #pragma unroll
      for (int i = 0; i < 4; ++i) {
        const int kst_m = (wid * 4 + i) - (inp ? 0 : 16);
        const int ko = kst_m * 32 + lq * 8;
        #pragma unroll
        for (int nt = 0; nt < 4; ++nt) {
          const int b = nt * 16 + lr;
          short8v Bh, Bl;
          ldB(bbase, ko, b, Bh, Bl);
          #pragma unroll
          for (int mt = 0; mt < 2; ++mt) {
            acc[mt][nt] = MF(Ah[mt][i], Bh, acc[mt][nt]);
            acc[mt][nt] = MF(Al[mt][i], Bh, acc[mt][nt]);
            acc[mt][nt] = MF(Ah[mt][i], Bl, acc[mt][nt]);
          }
        }
      }
    } else {
      #pragma unroll
      for (int i = 0; i < 2; ++i) {
        const int ko = (wid * 2 + i) * 32 + lq * 8;
        #pragma unroll
        for (int nt = 0; nt < 4; ++nt) {
          const int b = nt * 16 + lr;
          short8v Bh, Bl;
          ldB(h0p, ko, b, Bh, Bl);
          #pragma unroll
          for (int mt = 0; mt < 2; ++mt) {
            acc[mt][nt] = MF(Ah[mt][i], Bh, acc[mt][nt]);
            acc[mt][nt] = MF(Al[mt][i], Bh, acc[mt][nt]);
            acc[mt][nt] = MF(Ah[mt][i], Bl, acc[mt][nt]);
          }
        }
      }
    }

    // ---- write partials to LDS (stride 68: measured conflict-free) ----
    #pragma unroll
    for (int mt = 0; mt < 2; ++mt)
      #pragma unroll
      for (int nt = 0; nt < 4; ++nt)
        #pragma unroll
        for (int q = 0; q < 4; ++q)
          red[(wid * 32 + mt * 16 + lq * 4 + q) * 68 + nt * 16 + lr] = acc[mt][nt][q];
    __syncthreads();

    // ---- reduce + gates + packed coalesced store (thread: j=jth, b=bth) ----
    {
      float Sr = 0.f, Sz = 0.f, Sni = 0.f, Snh = 0.f;
      #pragma unroll
      for (int w = 0; w < 8; ++w) {
        Sr  += red[(w * 32 + jth) * 68 + bth];
        Sz  += red[(w * 32 + 8 + jth) * 68 + bth];
        Sni += red[(w * 32 + 16 + jth) * 68 + bth];
        Snh += red[(w * 32 + 24 + jth) * 68 + bth];
      }
      const float r = 1.f / (1.f + __expf(-(Sr + br)));
      const float z = 1.f / (1.f + __expf(-(Sz + bz)));
      const float n = tanhf(Sni + bnih + r * (Snh + bnhh));
      const unsigned idx = (unsigned)(j0 + jth) * 64u + (unsigned)bth;  // [k][b]
      const unsigned *hp; unsigned *hw;
      if (layer) {
        hp = ws32 + O_H1_W + ((unsigned)dir * 2 + (s & 1)) * 32768u;
        hw = ws32 + O_H1_W + ((unsigned)dir * 2 + ((s - 1) & 1)) * 32768u;
      } else {
        hp = ws32 + O_H0_W + ((unsigned)dir * 4 + ((s - 1) & 3)) * 32768u;
        hw = ws32 + O_H0_W + ((unsigned)dir * 4 + (s & 3)) * 32768u;
      }
      const unsigned pw0 = ald_w(hp + idx);
      const float hpv = bf16_f((unsigned short)(pw0 >> 16)) + bf16_f((unsigned short)(pw0 & 0xFFFFu));
      const float h = (1.f - z) * n + z * hpv;
      const unsigned short hh = bf16_rne(h);
      const unsigned short hl = bf16_rne(h - bf16_f(hh));
      ast_w(hw + idx, ((unsigned)hh << 16) | (unsigned)hl);
    }
    // __syncthreads drains vmcnt(0) => all h-stores at coherence point first
    __syncthreads();
    if (tid == 0)
      __hip_atomic_fetch_add(Lown + g8 * 16, 1, __ATOMIC_RELAXED, __HIP_MEMORY_SCOPE_AGENT);
  }
}

// ---- prep: fp32 -> bf16 hi/lo split (weights) ----
__global__ void cvt_k(const float* __restrict__ src, unsigned short* __restrict__ hi,
                      unsigned short* __restrict__ lo, int n) {
  for (int i = blockIdx.x * blockDim.x + threadIdx.x; i < n; i += gridDim.x * blockDim.x) {
    const float w = src[i];
    const unsigned short h = bf16_rne(w);
    hi[i] = h;
    lo[i] = bf16_rne(w - bf16_f(h));
  }
}

__global__ void init_k(unsigned* ws32, int* flags) {
  for (unsigned i = blockIdx.x * blockDim.x + threadIdx.x; i < H_ZERO_W; i += gridDim.x * blockDim.x)
    ws32[O_H0_W + i] = 0u;
  const unsigned g = blockIdx.x * blockDim.x + threadIdx.x;
  if (g < 512) flags[g] = 0;   // monotonic counters start at 0
}

// hidden = [h0_f | h1_f | h0_b | h1_b]; h0 final slot 3, h1 final slot 1
__global__ void gather_k(const unsigned* __restrict__ ws32, float* __restrict__ fc_in) {
  const int idx = blockIdx.x * blockDim.x + threadIdx.x;  // 64*2048
  const int b = idx >> 11, c = idx & 2047;
  const int seg = c >> 9, cc = c & 511;
  unsigned base;
  if (seg == 0)      base = O_H0_W + 3u * 32768u;
  else if (seg == 1) base = O_H1_W + 1u * 32768u;
  else if (seg == 2) base = O_H0_W + 7u * 32768u;
  else               base = O_H1_W + 3u * 32768u;
  const unsigned w = ws32[base + (unsigned)cc * 64u + (unsigned)b];
  fc_in[idx] = bf16_f((unsigned short)(w >> 16)) + bf16_f((unsigned short)(w & 0xFFFFu));
}

__global__ void fc_k(const float* __restrict__ in, const float* __restrict__ W,
                     const float* __restrict__ bias, float* __restrict__ out,
                     int K, int N, int leaky) {
  const int idx = blockIdx.x * blockDim.x + threadIdx.x;
  const int b = idx / N;
  const int n = idx - b * N;
  if (b >= BB) return;
  const float* ir = in + (size_t)b * K;
  const float* wr = W + (size_t)n * K;
  float acc = 0.f;
  for (int k = 0; k < K; k += 4) {
    const float4 a = *(const float4*)(ir + k);
    const float4 w = *(const float4*)(wr + k);
    acc += a.x * w.x + a.y * w.y + a.z * w.z + a.w * w.w;
  }
  acc += bias[n];
  if (leaky) acc = acc > 0.f ? acc : 0.01f * acc;
  out[idx] = acc;
}

extern "C" void kernel_launch(void* const* d_in, const int* in_sizes, int n_in,
                              void* d_out, int out_size, void* d_ws, size_t ws_size,
                              hipStream_t stream) {
  (void)in_sizes; (void)n_in; (void)out_size; (void)ws_size;

  PP P;
  P.x = (const float*)d_in[0];
  const float* Wih[4]; const float* Whh[4];
  for (int dir = 0; dir < 2; ++dir)
    for (int l = 0; l < 2; ++l) {
      const int base = 1 + (dir * 2 + l) * 4;
      const int u = dir * 2 + l;
      Wih[u] = (const float*)d_in[base + 0];
      Whh[u] = (const float*)d_in[base + 1];
      P.bih[u] = (const float*)d_in[base + 2];
      P.bhh[u] = (const float*)d_in[base + 3];
    }
  const float* Wfc0 = (const float*)d_in[17];
  const float* bfc0 = (const float*)d_in[18];
  const float* Wfc1 = (const float*)d_in[19];
  const float* bfc1 = (const float*)d_in[20];
  const float* Wfc2 = (const float*)d_in[21];
  const float* bfc2 = (const float*)d_in[22];

  unsigned short* wsu = (unsigned short*)d_ws;
  unsigned* ws32 = (unsigned*)d_ws;
  float* wsf = (float*)d_ws;
  int* flags = (int*)(ws32 + O_FLAGS_W);
  float* fc_in = wsf + O_FCIN_W;
  float* fc1o  = wsf + O_FC1O_W;
  float* fc2o  = wsf + O_FC2O_W;
  P.wsu = wsu; P.ws32 = ws32; P.flags = flags;

  hipFuncSetAttribute((const void*)gru_mfma,
                      hipFuncAttributeMaxDynamicSharedMemorySize, DYN_LDS);

  // ---- prep: weight split + h/flag init ----
  for (int u = 0; u < 4; ++u)
    hipLaunchKernelGGL(cvt_k, dim3(512), dim3(256), 0, stream,
                       Whh[u], wsu + O_WHH_HI + u * 786432u, wsu + O_WHH_LO + u * 786432u, 786432);
  for (int dir = 0; dir < 2; ++dir) {
    hipLaunchKernelGGL(cvt_k, dim3(512), dim3(256), 0, stream,
                       Wih[dir * 2 + 1], wsu + O_WIH1_HI + dir * 786432u, wsu + O_WIH1_LO + dir * 786432u, 786432);
    hipLaunchKernelGGL(cvt_k, dim3(256), dim3(256), 0, stream,
                       Wih[dir * 2 + 0], wsu + O_WIH0_HI + dir * 196608u, wsu + O_WIH0_LO + dir * 196608u, 196608);
  }
  hipLaunchKernelGGL(init_k, dim3(512), dim3(256), 0, stream, ws32, flags);

  // ---- persistent recurrence ----
  hipLaunchKernelGGL(gru_mfma, dim3(256), dim3(512), DYN_LDS, stream, P);

  // ---- FC head ----
  hipLaunchKernelGGL(gather_k, dim3(512), dim3(256), 0, stream, ws32, fc_in);
  hipLaunchKernelGGL(fc_k, dim3(256), dim3(256), 0, stream, fc_in, Wfc0, bfc0, fc1o, 2048, 1024, 1);
  hipLaunchKernelGGL(fc_k, dim3(128), dim3(256), 0, stream, fc1o, Wfc1, bfc1, fc2o, 1024, 512, 1);
  hipLaunchKernelGGL(fc_k, dim3(1), dim3(256), 0, stream, fc2o, Wfc2, bfc2, (float*)d_out, 512, 1, 0);
}

// Round 11
// 7026.235 us; speedup vs baseline: 1.5309x; 1.5309x over previous
//
#include <hip/hip_runtime.h>
#include <math.h>

typedef __attribute__((ext_vector_type(8))) short short8v;
typedef __attribute__((ext_vector_type(4))) float float4v;
typedef __attribute__((ext_vector_type(4))) unsigned uint4v;

#define BB 64
#define TT 1024
#define DD 128
#define HH 512

// ---- ushort (bf16) region: weights (element offsets) ----
#define O_WHH_HI  0u         // [4 units][1536][512]
#define O_WHH_LO  3145728u
#define O_WIH1_HI 6291456u   // [2 dir][1536][512]
#define O_WIH1_LO 7864320u
#define O_WIH0_HI 9437184u   // [2 dir][1536][128]
#define O_WIH0_LO 9830400u   // ends at 10223616 ushorts
// ---- 4-byte-word region (ws as unsigned*/float*), word offsets ----
// h planes tiled [k/8][64 b][8 e]: word = (k>>3)*512 + b*8 + (k&7)
#define O_H0_W    5111808u   // [2 dir][4 slot] planes of 32768 words
#define O_H1_W    5373952u   // [2 dir][4 slot] planes of 32768 words
#define O_FLAGS_W 5636096u   // 256 ints: cnt[u][slot]=f[u*32+slot]; gen[u]=f[128+u*32]
#define O_FCIN_W  5636352u   // 131072 f
#define O_FC1O_W  5767424u   //  65536 f
#define O_FC2O_W  5832960u   //  32768 f
#define H_ZERO_W  524288u    // words to zero from O_H0_W (h0 + h1, 4 slots each)

#define DYN_LDS   69632      // [8 waves][32 rows] x stride-68 f32 (measured conflict-free)

struct PP {
  const float* x;
  const float* bih[4];
  const float* bhh[4];
  unsigned short* wsu;   // weight planes
  unsigned* ws32;        // packed h region
  int* flags;
};

__device__ __forceinline__ unsigned short bf16_rne(float f) {
  unsigned u = __builtin_bit_cast(unsigned, f);
  u += 0x7FFFu + ((u >> 16) & 1u);
  return (unsigned short)(u >> 16);
}
__device__ __forceinline__ float bf16_f(unsigned short h) {
  unsigned u = ((unsigned)h) << 16;
  return __builtin_bit_cast(float, u);
}
__device__ __forceinline__ float4v MF(short8v a, short8v b, float4v c) {
  return __builtin_amdgcn_mfma_f32_16x16x32_bf16(a, b, c, 0, 0, 0);
}
// producer: agent-scope relaxed write-through (data lands at MALL, no dirty L2)
__device__ __forceinline__ void ast_w(unsigned* p, unsigned v) {
  __hip_atomic_store(p, v, __ATOMIC_RELAXED, __HIP_MEMORY_SCOPE_AGENT);
}
// consumer: PLAIN cached vector loads; coherent because (a) producers write-through,
// (b) every block does an agent-acquire (buffer_inv of L1+XCD-L2) each 4 steps,
// (c) slot rotation depth 4 on h0 AND h1 bounds any cached line's age < 4 steps,
// (d) anti-dep thresholds bound producer/consumer skew <= 3 steps.
__device__ __forceinline__ void ldB(const unsigned* base, int ko, int b,
                                    short8v& Bh, short8v& Bl) {
  const unsigned* q = base + ((unsigned)(ko >> 3) * 512u) + ((unsigned)b * 8u);
  const uint4v d0 = *(const uint4v*)q;
  const uint4v d1 = *(const uint4v*)(q + 4);
  #pragma unroll
  for (int i = 0; i < 4; ++i) {
    Bh[i]     = (short)(d0[i] >> 16);  Bl[i]     = (short)(d0[i] & 0xFFFFu);
    Bh[4 + i] = (short)(d1[i] >> 16);  Bl[4 + i] = (short)(d1[i] & 0xFFFFu);
  }
}

// row within stacked-[3*512] W for local row rl (0..31); -1 => zero frag
__device__ __forceinline__ int rowmap(int rl, int inp, int j0) {
  if (rl < 8)  return j0 + rl;
  if (rl < 16) return 512 + j0 + (rl - 8);
  if (rl < 24) return inp ? (1024 + j0 + rl - 16) : -1;
  return inp ? -1 : (1024 + j0 + rl - 24);
}
__device__ __forceinline__ short8v ldA(const unsigned short* W, int K, int row, int kofs) {
  return *(const short8v*)(W + (size_t)row * K + kofs);
}

// 256 blocks x 512 thr. u=bid>>6 (dir*2+layer), jt=bid&63 -> 8 j's.
// 8 waves split K; MFMA C[32 rows x 64 b]; rows: 0-7 r, 8-15 z, 16-23 n_ih, 24-31 n_hh.
// Sync: R6 single-level counter (64-way) + per-unit generation word.
// h slots: L0 writes s&3, reads (s-1)&3. L1 writes (s-1)&3, reads h1 (s-2)&3, h0 (s-1)&3.
__global__ __launch_bounds__(512) void gru_mfma(PP p) {
  extern __shared__ float red[];  // [8][32] stride 68
  const int bid = blockIdx.x;
  const int u = bid >> 6, dir = u >> 1, layer = u & 1;
  const int jt = bid & 63, j0 = jt * 8;
  const int tid = threadIdx.x, wid = tid >> 6, lane = tid & 63;
  const int lr = lane & 15, lq = lane >> 4;
  unsigned short* wsu = p.wsu;
  unsigned* ws32 = p.ws32;

  // ---- preload A fragments (weights) into VGPRs (normal cached loads) ----
  short8v Ah[2][4], Al[2][4];
  #pragma unroll
  for (int mt = 0; mt < 2; ++mt)
    #pragma unroll
    for (int i = 0; i < 4; ++i) { Ah[mt][i] = (short8v)0; Al[mt][i] = (short8v)0; }

  if (layer) {
    const int inp = (wid < 4);  // waves 0-3: input part (Wih_l1), 4-7: hidden (Whh)
    const unsigned short* Whi = inp ? (wsu + O_WIH1_HI + dir * 786432u)
                                    : (wsu + O_WHH_HI + (unsigned)u * 786432u);
    const unsigned short* Wlo = inp ? (wsu + O_WIH1_LO + dir * 786432u)
                                    : (wsu + O_WHH_LO + (unsigned)u * 786432u);
    #pragma unroll
    for (int i = 0; i < 4; ++i) {
      const int kst_m = (wid * 4 + i) - (inp ? 0 : 16);
      const int kofs = kst_m * 32 + lq * 8;
      #pragma unroll
      for (int mt = 0; mt < 2; ++mt) {
        const int row = rowmap(mt * 16 + lr, inp, j0);
        if (row >= 0) { Ah[mt][i] = ldA(Whi, 512, row, kofs); Al[mt][i] = ldA(Wlo, 512, row, kofs); }
      }
    }
  } else {
    const unsigned short* Whi = wsu + O_WHH_HI + (unsigned)u * 786432u;
    const unsigned short* Wlo = wsu + O_WHH_LO + (unsigned)u * 786432u;
    #pragma unroll
    for (int i = 0; i < 2; ++i) {
      const int kofs = (wid * 2 + i) * 32 + lq * 8;
      #pragma unroll
      for (int mt = 0; mt < 2; ++mt) {
        const int row = rowmap(mt * 16 + lr, 0, j0);
        if (row >= 0) { Ah[mt][i] = ldA(Whi, 512, row, kofs); Al[mt][i] = ldA(Wlo, 512, row, kofs); }
      }
    }
    if (wid < 4) {  // x part: K=128, wave wid owns kst wid
      const unsigned short* Xhi = wsu + O_WIH0_HI + dir * 196608u;
      const unsigned short* Xlo = wsu + O_WIH0_LO + dir * 196608u;
      const int kofs = wid * 32 + lq * 8;
      #pragma unroll
      for (int mt = 0; mt < 2; ++mt) {
        const int row = rowmap(mt * 16 + lr, 1, j0);
        if (row >= 0) { Ah[mt][2] = ldA(Xhi, 128, row, kofs); Al[mt][2] = ldA(Xlo, 128, row, kofs); }
      }
    }
  }

  // ---- gate-stage mapping: jl = tid&7 (j), bth = tid>>3 (batch) ----
  const int jl = tid & 7, bth = tid >> 3;
  const float br   = p.bih[u][j0 + jl] + p.bhh[u][j0 + jl];
  const float bz   = p.bih[u][512 + j0 + jl] + p.bhh[u][512 + j0 + jl];
  const float bnih = p.bih[u][1024 + j0 + jl];
  const float bnhh = p.bhh[u][1024 + j0 + jl];

  const int usib = layer ? (u - 1) : (u + 1);
  int* cntU   = p.flags + u * 32;            // 4 rotating slots
  int* genOwn = p.flags + 128 + u * 32;
  int* genSib = p.flags + 128 + usib * 32;
  const int sBeg = layer ? 1 : 0;
  const int sEnd = layer ? TT : (TT - 1);

  for (int s = sBeg; s <= sEnd; ++s) {
    const int t = layer ? (s - 1) : s;

    float4v acc[2][4];
    #pragma unroll
    for (int mt = 0; mt < 2; ++mt)
      #pragma unroll
      for (int nt = 0; nt < 4; ++nt) acc[mt][nt] = (float4v)0.f;

    // ---- x contribution BEFORE the wait (independent of h; hides x fetch) ----
    if (!layer && wid < 4) {
      const int tx = dir ? (TT - 1 - t) : t;
      const int ko = wid * 32 + lq * 8;
      #pragma unroll
      for (int nt = 0; nt < 4; ++nt) {
        const int b = nt * 16 + lr;
        const float* xs = p.x + ((size_t)b * TT + tx) * DD + ko;
        short8v Bh, Bl;
        #pragma unroll
        for (int e = 0; e < 8; ++e) {
          const float xv = xs[e];
          const unsigned short hh = bf16_rne(xv);
          Bh[e] = (short)hh;
          Bl[e] = (short)bf16_rne(xv - bf16_f(hh));
        }
        #pragma unroll
        for (int mt = 0; mt < 2; ++mt) {
          acc[mt][nt] = MF(Ah[mt][2], Bh, acc[mt][nt]);
          acc[mt][nt] = MF(Al[mt][2], Bh, acc[mt][nt]);
          acc[mt][nt] = MF(Ah[mt][2], Bl, acc[mt][nt]);
        }
      }
    }

    // ---- wait: poll two generation words (relaxed); inv L1/L2 every 4 steps ----
    if (wid == 0) {
      const int T1 = s - 1;
      const int T2 = layer ? (s - 1) : (s - 3);
      int iter = 0;
      while (true) {
        const int g1 = __hip_atomic_load(genOwn, __ATOMIC_RELAXED, __HIP_MEMORY_SCOPE_AGENT);
        const int g2 = __hip_atomic_load(genSib, __ATOMIC_RELAXED, __HIP_MEMORY_SCOPE_AGENT);
        if (g1 >= T1 && g2 >= T2) break;
        if (++iter > 2000000) {  // failsafe: no hang; release others and proceed
          if (lane == 0)
            __hip_atomic_store(genOwn, 1 << 29, __ATOMIC_RELAXED, __HIP_MEMORY_SCOPE_AGENT);
          break;
        }
        __builtin_amdgcn_s_sleep(2);
      }
      // Every 4th step: agent-acquire => buffer_inv (invalidate-only, L1 + XCD L2).
      // No dirty lines exist (all gru stores are sc1 write-through), so this only
      // discards stale clean copies. Slot depth 4 + skew<=3 makes cached reads safe
      // for the following 4 steps (see header comment).
      if ((s & 3) == 0)
        (void)__hip_atomic_load(genOwn, __ATOMIC_ACQUIRE, __HIP_MEMORY_SCOPE_AGENT);
    }
    __syncthreads();

    // ---- h contributions (tiled planes, cached dwordx4 loads) ----
    const unsigned* h0p = ws32 + O_H0_W + ((unsigned)dir * 4 + ((s - 1) & 3)) * 32768u;
    if (layer) {
      const int inp = (wid < 4);
      const unsigned* bbase = inp ? h0p
          : (ws32 + O_H1_W + ((unsigned)dir * 4 + ((s - 2) & 3)) * 32768u);
      #pragma unroll
      for (int i = 0; i < 4; ++i) {
        const int kst_m = (wid * 4 + i) - (inp ? 0 : 16);
        const int ko = kst_m * 32 + lq * 8;
        #pragma unroll
        for (int nt = 0; nt < 4; ++nt) {
          const int b = nt * 16 + lr;
          short8v Bh, Bl;
          ldB(bbase, ko, b, Bh, Bl);
          #pragma unroll
          for (int mt = 0; mt < 2; ++mt) {
            acc[mt][nt] = MF(Ah[mt][i], Bh, acc[mt][nt]);
            acc[mt][nt] = MF(Al[mt][i], Bh, acc[mt][nt]);
            acc[mt][nt] = MF(Ah[mt][i], Bl, acc[mt][nt]);
          }
        }
      }
    } else {
      #pragma unroll
      for (int i = 0; i < 2; ++i) {
        const int ko = (wid * 2 + i) * 32 + lq * 8;
        #pragma unroll
        for (int nt = 0; nt < 4; ++nt) {
          const int b = nt * 16 + lr;
          short8v Bh, Bl;
          ldB(h0p, ko, b, Bh, Bl);
          #pragma unroll
          for (int mt = 0; mt < 2; ++mt) {
            acc[mt][nt] = MF(Ah[mt][i], Bh, acc[mt][nt]);
            acc[mt][nt] = MF(Al[mt][i], Bh, acc[mt][nt]);
            acc[mt][nt] = MF(Ah[mt][i], Bl, acc[mt][nt]);
          }
        }
      }
    }

    // ---- write partials to LDS (stride 68: measured conflict-free) ----
    #pragma unroll
    for (int mt = 0; mt < 2; ++mt)
      #pragma unroll
      for (int nt = 0; nt < 4; ++nt)
        #pragma unroll
        for (int q = 0; q < 4; ++q)
          red[(wid * 32 + mt * 16 + lq * 4 + q) * 68 + nt * 16 + lr] = acc[mt][nt][q];
    __syncthreads();

    // ---- reduce + gates + packed coalesced store (thread: j=jl, b=bth) ----
    {
      float Sr = 0.f, Sz = 0.f, Sni = 0.f, Snh = 0.f;
      #pragma unroll
      for (int w = 0; w < 8; ++w) {
        Sr  += red[(w * 32 + jl) * 68 + bth];
        Sz  += red[(w * 32 + 8 + jl) * 68 + bth];
        Sni += red[(w * 32 + 16 + jl) * 68 + bth];
        Snh += red[(w * 32 + 24 + jl) * 68 + bth];
      }
      const float r = 1.f / (1.f + __expf(-(Sr + br)));
      const float z = 1.f / (1.f + __expf(-(Sz + bz)));
      const float n = tanhf(Sni + bnih + r * (Snh + bnhh));
      // tiled word addr for (k = j0+jl, b = bth): (k>>3)=jt, (k&7)=jl
      const unsigned idx = (unsigned)jt * 512u + (unsigned)bth * 8u + (unsigned)jl;
      const unsigned *hp; unsigned *hw;
      if (layer) {
        hp = ws32 + O_H1_W + ((unsigned)dir * 4 + ((s - 2) & 3)) * 32768u;
        hw = ws32 + O_H1_W + ((unsigned)dir * 4 + ((s - 1) & 3)) * 32768u;
      } else {
        hp = ws32 + O_H0_W + ((unsigned)dir * 4 + ((s - 1) & 3)) * 32768u;
        hw = ws32 + O_H0_W + ((unsigned)dir * 4 + (s & 3)) * 32768u;
      }
      const unsigned pw0 = hp[idx];  // plain cached: covered by 4-step inv window
      const float hpv = bf16_f((unsigned short)(pw0 >> 16)) + bf16_f((unsigned short)(pw0 & 0xFFFFu));
      const float h = (1.f - z) * n + z * hpv;
      const unsigned short hh = bf16_rne(h);
      const unsigned short hl = bf16_rne(h - bf16_f(hh));
      ast_w(hw + idx, ((unsigned)hh << 16) | (unsigned)hl);
    }
    // __syncthreads drains vmcnt(0) => all write-through h-stores at MALL first
    __syncthreads();
    if (tid == 0) {
      const int old = __hip_atomic_fetch_add(cntU + (s & 3), 1, __ATOMIC_RELAXED,
                                             __HIP_MEMORY_SCOPE_AGENT);
      if (old == 63) {  // last arrival: recycle slot s+2, then publish generation s
        __hip_atomic_store(cntU + ((s + 2) & 3), 0, __ATOMIC_RELAXED, __HIP_MEMORY_SCOPE_AGENT);
        __hip_atomic_store(genOwn, s, __ATOMIC_RELAXED, __HIP_MEMORY_SCOPE_AGENT);
      }
    }
  }
}

// ---- prep: fp32 -> bf16 hi/lo split (weights) ----
__global__ void cvt_k(const float* __restrict__ src, unsigned short* __restrict__ hi,
                      unsigned short* __restrict__ lo, int n) {
  for (int i = blockIdx.x * blockDim.x + threadIdx.x; i < n; i += gridDim.x * blockDim.x) {
    const float w = src[i];
    const unsigned short h = bf16_rne(w);
    hi[i] = h;
    lo[i] = bf16_rne(w - bf16_f(h));
  }
}

__global__ void init_k(unsigned* ws32, int* flags) {
  for (unsigned i = blockIdx.x * blockDim.x + threadIdx.x; i < H_ZERO_W; i += gridDim.x * blockDim.x)
    ws32[O_H0_W + i] = 0u;
  const unsigned g = blockIdx.x * blockDim.x + threadIdx.x;
  if (g < 256) {
    int v = 0;
    if (g >= 128 && ((g - 128) & 31) == 0) {
      const unsigned uu = (g - 128) >> 5;     // gen[u]: L1 units (u odd) start 0, L0 -1
      v = (uu & 1) ? 0 : -1;
    }
    flags[g] = v;
  }
}

// hidden = [h0_f | h1_f | h0_b | h1_b]; h0 final slot 1023&3=3, h1 final slot 1023&3=3
__global__ void gather_k(const unsigned* __restrict__ ws32, float* __restrict__ fc_in) {
  const int idx = blockIdx.x * blockDim.x + threadIdx.x;  // 64*2048
  const int b = idx >> 11, c = idx & 2047;
  const int seg = c >> 9, cc = c & 511;
  unsigned base;
  if (seg == 0)      base = O_H0_W + 3u * 32768u;
  else if (seg == 1) base = O_H1_W + 3u * 32768u;
  else if (seg == 2) base = O_H0_W + 7u * 32768u;
  else               base = O_H1_W + 7u * 32768u;
  const unsigned w = ws32[base + (unsigned)(cc >> 3) * 512u + (unsigned)b * 8u + (unsigned)(cc & 7)];
  fc_in[idx] = bf16_f((unsigned short)(w >> 16)) + bf16_f((unsigned short)(w & 0xFFFFu));
}

__global__ void fc_k(const float* __restrict__ in, const float* __restrict__ W,
                     const float* __restrict__ bias, float* __restrict__ out,
                     int K, int N, int leaky) {
  const int idx = blockIdx.x * blockDim.x + threadIdx.x;
  const int b = idx / N;
  const int n = idx - b * N;
  if (b >= BB) return;
  const float* ir = in + (size_t)b * K;
  const float* wr = W + (size_t)n * K;
  float acc = 0.f;
  for (int k = 0; k < K; k += 4) {
    const float4 a = *(const float4*)(ir + k);
    const float4 w = *(const float4*)(wr + k);
    acc += a.x * w.x + a.y * w.y + a.z * w.z + a.w * w.w;
  }
  acc += bias[n];
  if (leaky) acc = acc > 0.f ? acc : 0.01f * acc;
  out[idx] = acc;
}

extern "C" void kernel_launch(void* const* d_in, const int* in_sizes, int n_in,
                              void* d_out, int out_size, void* d_ws, size_t ws_size,
                              hipStream_t stream) {
  (void)in_sizes; (void)n_in; (void)out_size; (void)ws_size;

  PP P;
  P.x = (const float*)d_in[0];
  const float* Wih[4]; const float* Whh[4];
  for (int dir = 0; dir < 2; ++dir)
    for (int l = 0; l < 2; ++l) {
      const int base = 1 + (dir * 2 + l) * 4;
      const int u = dir * 2 + l;
      Wih[u] = (const float*)d_in[base + 0];
      Whh[u] = (const float*)d_in[base + 1];
      P.bih[u] = (const float*)d_in[base + 2];
      P.bhh[u] = (const float*)d_in[base + 3];
    }
  const float* Wfc0 = (const float*)d_in[17];
  const float* bfc0 = (const float*)d_in[18];
  const float* Wfc1 = (const float*)d_in[19];
  const float* bfc1 = (const float*)d_in[20];
  const float* Wfc2 = (const float*)d_in[21];
  const float* bfc2 = (const float*)d_in[22];

  unsigned short* wsu = (unsigned short*)d_ws;
  unsigned* ws32 = (unsigned*)d_ws;
  float* wsf = (float*)d_ws;
  int* flags = (int*)(ws32 + O_FLAGS_W);
  float* fc_in = wsf + O_FCIN_W;
  float* fc1o  = wsf + O_FC1O_W;
  float* fc2o  = wsf + O_FC2O_W;
  P.wsu = wsu; P.ws32 = ws32; P.flags = flags;

  hipFuncSetAttribute((const void*)gru_mfma,
                      hipFuncAttributeMaxDynamicSharedMemorySize, DYN_LDS);

  // ---- prep: weight split + h/flag init ----
  for (int u = 0; u < 4; ++u)
    hipLaunchKernelGGL(cvt_k, dim3(512), dim3(256), 0, stream,
                       Whh[u], wsu + O_WHH_HI + u * 786432u, wsu + O_WHH_LO + u * 786432u, 786432);
  for (int dir = 0; dir < 2; ++dir) {
    hipLaunchKernelGGL(cvt_k, dim3(512), dim3(256), 0, stream,
                       Wih[dir * 2 + 1], wsu + O_WIH1_HI + dir * 786432u, wsu + O_WIH1_LO + dir * 786432u, 786432);
    hipLaunchKernelGGL(cvt_k, dim3(256), dim3(256), 0, stream,
                       Wih[dir * 2 + 0], wsu + O_WIH0_HI + dir * 196608u, wsu + O_WIH0_LO + dir * 196608u, 196608);
  }
  hipLaunchKernelGGL(init_k, dim3(1024), dim3(256), 0, stream, ws32, flags);

  // ---- persistent recurrence ----
  hipLaunchKernelGGL(gru_mfma, dim3(256), dim3(512), DYN_LDS, stream, P);

  // ---- FC head ----
  hipLaunchKernelGGL(gather_k, dim3(512), dim3(256), 0, stream, ws32, fc_in);
  hipLaunchKernelGGL(fc_k, dim3(256), dim3(256), 0, stream, fc_in, Wfc0, bfc0, fc1o, 2048, 1024, 1);
  hipLaunchKernelGGL(fc_k, dim3(128), dim3(256), 0, stream, fc1o, Wfc1, bfc1, fc2o, 1024, 512, 1);
  hipLaunchKernelGGL(fc_k, dim3(1), dim3(256), 0, stream, fc2o, Wfc2, bfc2, (float*)d_out, 512, 1, 0);
}